// Round 9
// baseline (122.401 us; speedup 1.0000x reference)
//
#include <hip/hip_runtime.h>

#define N_NODES 50000
#define K_DEG   17
#define DIN     128
#define DOUT    64

typedef _Float16 f16;
typedef __attribute__((ext_vector_type(8))) short  short8;   // bf16 A/B frag (4 VGPR)
typedef __attribute__((ext_vector_type(4))) float  floatx4;  // C/D frag

// ---------------------------------------------------------------------------
// Batcher merge-exchange sorting network (compile-time; fully unrolls).
// ---------------------------------------------------------------------------
struct CEPair { unsigned char a, b; };

constexpr int net_count(int n) {
  int t = 0; while ((1 << t) < n) ++t;
  int cnt = 0;
  for (int p = 1 << (t - 1); p > 0; p >>= 1) {
    int q = 1 << (t - 1), r = 0, d = p;
    for (;;) {
      for (int i = 0; i < n - d; ++i)
        if ((i & p) == r) ++cnt;
      if (q == p) break;
      d = q - p; q >>= 1; r = p;
    }
  }
  return cnt;
}

template <int NP> struct NetArr { CEPair v[NP]; };

template <int NP>
constexpr NetArr<NP> net_pairs(int n) {
  NetArr<NP> out{};
  int t = 0; while ((1 << t) < n) ++t;
  int cnt = 0;
  for (int p = 1 << (t - 1); p > 0; p >>= 1) {
    int q = 1 << (t - 1), r = 0, d = p;
    for (;;) {
      for (int i = 0; i < n - d; ++i)
        if ((i & p) == r) {
          out.v[cnt].a = (unsigned char)i;
          out.v[cnt].b = (unsigned char)(i + d);
          ++cnt;
        }
      if (q == p) break;
      d = q - p; q >>= 1; r = p;
    }
  }
  return out;
}

constexpr int NP17 = net_count(K_DEG);   // 74 compare-exchanges for n=17

// ---------------------------------------------------------------------------
// bf16 helpers (RNE)
// ---------------------------------------------------------------------------
__device__ __forceinline__ unsigned int f2bf(float f) {
  union { float f; unsigned int u; } c; c.f = f;
  return (c.u + 0x7FFFu + ((c.u >> 16) & 1u)) >> 16;
}
__device__ __forceinline__ float bf2f(unsigned int b) {
  union { float f; unsigned int u; } c; c.u = b << 16;
  return c.f;
}

// ---------------------------------------------------------------------------
// Kernel 0: convert W -> frag-ordered bf16 hi/lo table T (32 KB). Frozen.
// ---------------------------------------------------------------------------
__global__ void convw_kernel(const float* __restrict__ W,
                             unsigned short* __restrict__ T) {
  const int flat = blockIdx.x * 256 + threadIdx.x;   // 0..8191
  const int j    = flat & 7;
  const int lane = (flat >> 3) & 63;
  const int pair = flat >> 9;                        // 0..15
  const int ks   = pair >> 2, nt = pair & 3;
  const int k    = ks * 32 + (lane >> 4) * 8 + j;
  const int n    = nt * 16 + (lane & 15);
  const float f  = W[k * DOUT + n];
  const unsigned int hb = f2bf(f);
  const float        lo = f - bf2f(hb);
  const unsigned int lb = f2bf(lo);
  T[flat]        = (unsigned short)hb;
  T[flat + 8192] = (unsigned short)lb;
}

// ---------------------------------------------------------------------------
// Kernel 1: xp = x @ W via bf16 MFMA, 3-term hi/lo split; fp16 output.
// Frozen since R4/R8 (near its memory floor).
// ---------------------------------------------------------------------------
__global__ __launch_bounds__(256) void gemm_kernel(
    const float* __restrict__ x, const unsigned short* __restrict__ T,
    f16* __restrict__ xp) {
  const int gwave = blockIdx.x * 4 + (threadIdx.x >> 6);
  if (gwave >= (N_NODES / 16)) return;
  const int lane = threadIdx.x & 63;
  const int r0 = gwave * 16;
  const int m  = lane & 15;     // A row within tile
  const int q  = lane >> 4;     // k-quad

  const float4* x4 = (const float4*)x;
  float4 xr[8];
  #pragma unroll
  for (int ks = 0; ks < 4; ++ks) {
    const int base = (r0 + m) * (DIN / 4) + ks * 8 + q * 2;
    xr[ks * 2 + 0] = x4[base + 0];
    xr[ks * 2 + 1] = x4[base + 1];
  }

  floatx4 acc[4];
  #pragma unroll
  for (int nt = 0; nt < 4; ++nt) acc[nt] = (floatx4){0.f, 0.f, 0.f, 0.f};

  const short8* Th = (const short8*)T;
  const short8* Tl = (const short8*)(T + 8192);

  #pragma unroll
  for (int ks = 0; ks < 4; ++ks) {
    short8 Bh[4], Bl[4];
    #pragma unroll
    for (int nt = 0; nt < 4; ++nt) {
      const int fi = (ks * 4 + nt) * 64 + lane;
      Bh[nt] = Th[fi];
      Bl[nt] = Tl[fi];
    }
    float f[8] = {xr[ks*2].x, xr[ks*2].y, xr[ks*2].z, xr[ks*2].w,
                  xr[ks*2+1].x, xr[ks*2+1].y, xr[ks*2+1].z, xr[ks*2+1].w};
    union { unsigned int i[4]; short8 s; } Ah, Al;
    #pragma unroll
    for (int r = 0; r < 4; ++r) {
      const unsigned int h0 = f2bf(f[2*r]),   h1 = f2bf(f[2*r+1]);
      const unsigned int l0 = f2bf(f[2*r]   - bf2f(h0));
      const unsigned int l1 = f2bf(f[2*r+1] - bf2f(h1));
      Ah.i[r] = h0 | (h1 << 16);
      Al.i[r] = l0 | (l1 << 16);
    }
    #pragma unroll
    for (int nt = 0; nt < 4; ++nt) {
      acc[nt] = __builtin_amdgcn_mfma_f32_16x16x32_bf16(Al.s, Bh[nt], acc[nt], 0, 0, 0);
      acc[nt] = __builtin_amdgcn_mfma_f32_16x16x32_bf16(Ah.s, Bl[nt], acc[nt], 0, 0, 0);
      acc[nt] = __builtin_amdgcn_mfma_f32_16x16x32_bf16(Ah.s, Bh[nt], acc[nt], 0, 0, 0);
    }
  }

  #pragma unroll
  for (int nt = 0; nt < 4; ++nt) {
    const int col = nt * 16 + m;
    #pragma unroll
    for (int r = 0; r < 4; ++r)
      xp[(r0 + q * 4 + r) * DOUT + col] = (f16)acc[nt][r];
  }
}

// ---------------------------------------------------------------------------
// Kernel 2: weighted per-dim median + scale + bias.
// R9: node scalarized via readfirstlane of a COMPUTED index (no load in the
// chain — avoids R2's serialization): cp/wp become s_load, gather bases go
// SALU, voffset = lane*2 is loop-constant. rs replaced by sorted-order
// total (diff ~1 ulp of 8.5 -> output shift ~1e-5, invisible). w feeds only
// the LDS stash. Selection semantics unchanged: cumsum sequential in sorted
// order, total = last cum, first pos with cum >= 0.5*total.
// ---------------------------------------------------------------------------
__global__ __launch_bounds__(256, 2) void median_kernel(
    const f16* __restrict__ xp, const int* __restrict__ col,
    const float* __restrict__ ew, const float* __restrict__ bias,
    float* __restrict__ out) {
  __shared__ float wlds[4 * K_DEG * 64];     // [wave][j][lane], 17408 B

  const int wave = threadIdx.x >> 6;
  const int lane = threadIdx.x & 63;
  // wave-uniform by construction; readfirstlane makes it provably uniform
  const int node = __builtin_amdgcn_readfirstlane(blockIdx.x * 4 + wave);

  const int*   cp = col + node * K_DEG;      // uniform address -> s_load
  const float* wp = ew  + node * K_DEG;      // uniform address -> s_load

  // neighbor ids (uniform -> SGPRs; no per-lane address math)
  int c[K_DEG];
  #pragma unroll
  for (int j = 0; j < K_DEG; ++j) c[j] = cp[j];

  // gathers: SGPR base per j + constant voffset (lane*2 bytes)
  float v[K_DEG];
  #pragma unroll
  for (int j = 0; j < K_DEG; ++j)
    v[j] = (float)xp[c[j] * DOUT + lane];    // 128B coalesced fp16 gather

  // stash w in LDS (own lane's column; no cross-lane -> no barrier)
  float* wl = wlds + wave * (K_DEG * 64) + lane;
  #pragma unroll
  for (int j = 0; j < K_DEG; ++j) wl[j * 64] = wp[j];

  const float bl = bias[lane];

  // pack index j into mantissa LSBs (exact: cvt_f32_f16 leaves 13 zero LSBs)
  #pragma unroll
  for (int j = 0; j < K_DEG; ++j) {
    union { float f; unsigned int u; } c2; c2.f = v[j];
    c2.u |= (unsigned)j;
    v[j] = c2.f;
  }

  // sort v ascending — min/max-only compile-time Batcher network (2 ops/CE)
  constexpr NetArr<NP17> NET = net_pairs<NP17>(K_DEG);
  #pragma unroll
  for (int s = 0; s < NP17; ++s) {
    const int a = NET.v[s].a, b = NET.v[s].b;
    const float va = v[a], vb = v[b];
    v[a] = fminf(va, vb);
    v[b] = fmaxf(va, vb);
  }

  // recover w in sorted order: idx from LSBs -> LDS read (conflict-free)
  float sw[K_DEG];
  #pragma unroll
  for (int j = 0; j < K_DEG; ++j) {
    union { float f; unsigned int u; } c2; c2.f = v[j];
    sw[j] = wl[(c2.u & 31u) * 64];
  }

  // sequential cumsum in sorted order (exact reference order)
  float cum[K_DEG];
  float run = 0.f;
  #pragma unroll
  for (int j = 0; j < K_DEG; ++j) { run += sw[j]; cum[j] = run; }
  const float half = 0.5f * run;             // run == total == cum[-1]

  // first sorted position with cum >= half: backward cndmask scan
  float med = v[K_DEG - 1];
  #pragma unroll
  for (int j = K_DEG - 2; j >= 0; --j)
    med = (cum[j] >= half) ? v[j] : med;

  // scale by total (== row_sum up to ~1 ulp; output shift ~1e-5, harmless)
  out[node * DOUT + lane] = run * med + bl;
}

// ---------------------------------------------------------------------------
extern "C" void kernel_launch(void* const* d_in, const int* in_sizes, int n_in,
                              void* d_out, int out_size, void* d_ws, size_t ws_size,
                              hipStream_t stream) {
  const float* x    = (const float*)d_in[0];
  const int*   ei   = (const int*)d_in[1];
  const float* ew   = (const float*)d_in[2];
  const float* W    = (const float*)d_in[3];
  const float* bias = (const float*)d_in[4];
  float*       out  = (float*)d_out;

  f16*            xp = (f16*)d_ws;                              // 6.4 MB
  unsigned short* T  = (unsigned short*)((char*)d_ws + (size_t)N_NODES * DOUT * 2);
  const int*      colp = ei + (size_t)N_NODES * K_DEG;          // edge_index[1]

  convw_kernel<<<8192 / 256, 256, 0, stream>>>(W, T);
  gemm_kernel<<<(N_NODES / 16 + 3) / 4, 256, 0, stream>>>(x, T, xp);
  median_kernel<<<N_NODES / 4, 256, 0, stream>>>(xp, colp, ew, bias, out);
}

// Round 10
// 119.483 us; speedup vs baseline: 1.0244x; 1.0244x over previous
//
#include <hip/hip_runtime.h>

#define N_NODES 50000
#define K_DEG   17
#define DIN     128
#define DOUT    64

typedef _Float16 f16;
typedef __attribute__((ext_vector_type(8))) short  short8;   // bf16 A/B frag (4 VGPR)
typedef __attribute__((ext_vector_type(4))) float  floatx4;  // C/D frag

// ---------------------------------------------------------------------------
// Batcher merge-exchange sorting network (compile-time; fully unrolls).
// ---------------------------------------------------------------------------
struct CEPair { unsigned char a, b; };

constexpr int net_count(int n) {
  int t = 0; while ((1 << t) < n) ++t;
  int cnt = 0;
  for (int p = 1 << (t - 1); p > 0; p >>= 1) {
    int q = 1 << (t - 1), r = 0, d = p;
    for (;;) {
      for (int i = 0; i < n - d; ++i)
        if ((i & p) == r) ++cnt;
      if (q == p) break;
      d = q - p; q >>= 1; r = p;
    }
  }
  return cnt;
}

template <int NP> struct NetArr { CEPair v[NP]; };

template <int NP>
constexpr NetArr<NP> net_pairs(int n) {
  NetArr<NP> out{};
  int t = 0; while ((1 << t) < n) ++t;
  int cnt = 0;
  for (int p = 1 << (t - 1); p > 0; p >>= 1) {
    int q = 1 << (t - 1), r = 0, d = p;
    for (;;) {
      for (int i = 0; i < n - d; ++i)
        if ((i & p) == r) {
          out.v[cnt].a = (unsigned char)i;
          out.v[cnt].b = (unsigned char)(i + d);
          ++cnt;
        }
      if (q == p) break;
      d = q - p; q >>= 1; r = p;
    }
  }
  return out;
}

constexpr int NP17 = net_count(K_DEG);   // 74 compare-exchanges for n=17

// ---------------------------------------------------------------------------
// bf16 helpers (RNE)
// ---------------------------------------------------------------------------
__device__ __forceinline__ unsigned int f2bf(float f) {
  union { float f; unsigned int u; } c; c.f = f;
  return (c.u + 0x7FFFu + ((c.u >> 16) & 1u)) >> 16;
}
__device__ __forceinline__ float bf2f(unsigned int b) {
  union { float f; unsigned int u; } c; c.u = b << 16;
  return c.f;
}

// ---------------------------------------------------------------------------
// Kernel 0: convert W -> frag-ordered bf16 hi/lo table T (32 KB). Frozen.
// ---------------------------------------------------------------------------
__global__ void convw_kernel(const float* __restrict__ W,
                             unsigned short* __restrict__ T) {
  const int flat = blockIdx.x * 256 + threadIdx.x;   // 0..8191
  const int j    = flat & 7;
  const int lane = (flat >> 3) & 63;
  const int pair = flat >> 9;                        // 0..15
  const int ks   = pair >> 2, nt = pair & 3;
  const int k    = ks * 32 + (lane >> 4) * 8 + j;
  const int n    = nt * 16 + (lane & 15);
  const float f  = W[k * DOUT + n];
  const unsigned int hb = f2bf(f);
  const float        lo = f - bf2f(hb);
  const unsigned int lb = f2bf(lo);
  T[flat]        = (unsigned short)hb;
  T[flat + 8192] = (unsigned short)lb;
}

// ---------------------------------------------------------------------------
// Kernel 1: xp = x @ W via bf16 MFMA, 3-term hi/lo split; fp16 output.
// Frozen since R4/R8 (near its memory floor).
// ---------------------------------------------------------------------------
__global__ __launch_bounds__(256) void gemm_kernel(
    const float* __restrict__ x, const unsigned short* __restrict__ T,
    f16* __restrict__ xp) {
  const int gwave = blockIdx.x * 4 + (threadIdx.x >> 6);
  if (gwave >= (N_NODES / 16)) return;
  const int lane = threadIdx.x & 63;
  const int r0 = gwave * 16;
  const int m  = lane & 15;     // A row within tile
  const int q  = lane >> 4;     // k-quad

  const float4* x4 = (const float4*)x;
  float4 xr[8];
  #pragma unroll
  for (int ks = 0; ks < 4; ++ks) {
    const int base = (r0 + m) * (DIN / 4) + ks * 8 + q * 2;
    xr[ks * 2 + 0] = x4[base + 0];
    xr[ks * 2 + 1] = x4[base + 1];
  }

  floatx4 acc[4];
  #pragma unroll
  for (int nt = 0; nt < 4; ++nt) acc[nt] = (floatx4){0.f, 0.f, 0.f, 0.f};

  const short8* Th = (const short8*)T;
  const short8* Tl = (const short8*)(T + 8192);

  #pragma unroll
  for (int ks = 0; ks < 4; ++ks) {
    short8 Bh[4], Bl[4];
    #pragma unroll
    for (int nt = 0; nt < 4; ++nt) {
      const int fi = (ks * 4 + nt) * 64 + lane;
      Bh[nt] = Th[fi];
      Bl[nt] = Tl[fi];
    }
    float f[8] = {xr[ks*2].x, xr[ks*2].y, xr[ks*2].z, xr[ks*2].w,
                  xr[ks*2+1].x, xr[ks*2+1].y, xr[ks*2+1].z, xr[ks*2+1].w};
    union { unsigned int i[4]; short8 s; } Ah, Al;
    #pragma unroll
    for (int r = 0; r < 4; ++r) {
      const unsigned int h0 = f2bf(f[2*r]),   h1 = f2bf(f[2*r+1]);
      const unsigned int l0 = f2bf(f[2*r]   - bf2f(h0));
      const unsigned int l1 = f2bf(f[2*r+1] - bf2f(h1));
      Ah.i[r] = h0 | (h1 << 16);
      Al.i[r] = l0 | (l1 << 16);
    }
    #pragma unroll
    for (int nt = 0; nt < 4; ++nt) {
      acc[nt] = __builtin_amdgcn_mfma_f32_16x16x32_bf16(Al.s, Bh[nt], acc[nt], 0, 0, 0);
      acc[nt] = __builtin_amdgcn_mfma_f32_16x16x32_bf16(Ah.s, Bl[nt], acc[nt], 0, 0, 0);
      acc[nt] = __builtin_amdgcn_mfma_f32_16x16x32_bf16(Ah.s, Bh[nt], acc[nt], 0, 0, 0);
    }
  }

  #pragma unroll
  for (int nt = 0; nt < 4; ++nt) {
    const int col = nt * 16 + m;
    #pragma unroll
    for (int r = 0; r < 4; ++r)
      xp[(r0 + q * 4 + r) * DOUT + col] = (f16)acc[nt][r];
  }
}

// ---------------------------------------------------------------------------
// Kernel 2: weighted per-dim median + scale + bias.
// R10: w is wave-uniform (per-edge, same for all 64 dims) -> stash ONE copy
// per node in LDS (1 predicated ds_write vs 17), read back by sorted idx
// (17 consecutive words -> 17 distinct banks; same-address lanes broadcast
// -> conflict-free). LDS instrs/wave 34 -> 18; footprint 17KB -> 320B.
// All arithmetic and ordering bit-identical to R9 (cumsum sequential in
// sorted order, total = last cum, scale by total).
// ---------------------------------------------------------------------------
__global__ __launch_bounds__(256, 2) void median_kernel(
    const f16* __restrict__ xp, const int* __restrict__ col,
    const float* __restrict__ ew, const float* __restrict__ bias,
    float* __restrict__ out) {
  __shared__ float wlds[4 * 20];             // [wave][17 (+3 pad)]

  const int wave = threadIdx.x >> 6;
  const int lane = threadIdx.x & 63;
  // wave-uniform by construction; readfirstlane makes it provably uniform
  const int node = __builtin_amdgcn_readfirstlane(blockIdx.x * 4 + wave);

  const int*   cp = col + node * K_DEG;      // uniform address -> s_load
  const float* wp = ew  + node * K_DEG;      // uniform address

  // neighbor ids (uniform -> SGPRs)
  int c[K_DEG];
  #pragma unroll
  for (int j = 0; j < K_DEG; ++j) c[j] = cp[j];

  // gathers: SGPR base per j + per-lane voffset (lane*2 bytes)
  float v[K_DEG];
  #pragma unroll
  for (int j = 0; j < K_DEG; ++j)
    v[j] = (float)xp[c[j] * DOUT + lane];    // 128B coalesced fp16 gather

  // stash w ONCE per node: lanes 0..16 write one float each
  float* wl = wlds + wave * 20;
  if (lane < K_DEG) wl[lane] = wp[lane];

  const float bl = bias[lane];

  // pack index j into mantissa LSBs (exact: cvt_f32_f16 leaves 13 zero LSBs)
  #pragma unroll
  for (int j = 0; j < K_DEG; ++j) {
    union { float f; unsigned int u; } c2; c2.f = v[j];
    c2.u |= (unsigned)j;
    v[j] = c2.f;
  }

  // sort v ascending — min/max-only compile-time Batcher network (2 ops/CE)
  constexpr NetArr<NP17> NET = net_pairs<NP17>(K_DEG);
  #pragma unroll
  for (int s = 0; s < NP17; ++s) {
    const int a = NET.v[s].a, b = NET.v[s].b;
    const float va = v[a], vb = v[b];
    v[a] = fminf(va, vb);
    v[b] = fmaxf(va, vb);
  }

  // recover w in sorted order: idx from LSBs -> broadcast LDS read
  float sw[K_DEG];
  #pragma unroll
  for (int j = 0; j < K_DEG; ++j) {
    union { float f; unsigned int u; } c2; c2.f = v[j];
    sw[j] = wl[c2.u & 31u];
  }

  // sequential cumsum in sorted order (exact reference order)
  float cum[K_DEG];
  float run = 0.f;
  #pragma unroll
  for (int j = 0; j < K_DEG; ++j) { run += sw[j]; cum[j] = run; }
  const float half = 0.5f * run;             // run == total == cum[-1]

  // first sorted position with cum >= half: backward cndmask scan
  float med = v[K_DEG - 1];
  #pragma unroll
  for (int j = K_DEG - 2; j >= 0; --j)
    med = (cum[j] >= half) ? v[j] : med;

  // scale by total (== row_sum up to ~1 ulp; output shift ~1e-5, harmless)
  out[node * DOUT + lane] = run * med + bl;
}

// ---------------------------------------------------------------------------
extern "C" void kernel_launch(void* const* d_in, const int* in_sizes, int n_in,
                              void* d_out, int out_size, void* d_ws, size_t ws_size,
                              hipStream_t stream) {
  const float* x    = (const float*)d_in[0];
  const int*   ei   = (const int*)d_in[1];
  const float* ew   = (const float*)d_in[2];
  const float* W    = (const float*)d_in[3];
  const float* bias = (const float*)d_in[4];
  float*       out  = (float*)d_out;

  f16*            xp = (f16*)d_ws;                              // 6.4 MB
  unsigned short* T  = (unsigned short*)((char*)d_ws + (size_t)N_NODES * DOUT * 2);
  const int*      colp = ei + (size_t)N_NODES * K_DEG;          // edge_index[1]

  convw_kernel<<<8192 / 256, 256, 0, stream>>>(W, T);
  gemm_kernel<<<(N_NODES / 16 + 3) / 4, 256, 0, stream>>>(x, T, xp);
  median_kernel<<<N_NODES / 4, 256, 0, stream>>>(xp, colp, ew, bias, out);
}